// Round 13
// baseline (45.136 us; speedup 1.0000x reference)
//
#include <hip/hip_runtime.h>
#include <math.h>

#define NPTS 16384
#define NB   2
#define RPB  8192               // refs per block (streamed)
#define NRC  (NPTS / RPB)       // 2
#define NCH  8                  // chunks per block
#define CHREF 1024              // refs per chunk (32 KiB)
#define QPB  256                // queries per block: 4 waves * 2 frags * 32
#define NQC  (NPTS / QPB)       // 64
#define TOTQ (NB * NPTS)        // 32768
#define TOTMIN (2 * TOTQ)       // 65536

typedef short bf16x8 __attribute__((ext_vector_type(8)));

// monotone float <-> uint (t can be negative)
__device__ __forceinline__ unsigned ordf(float f) {
    unsigned b = __float_as_uint(f);
    return (b & 0x80000000u) ? ~b : (b | 0x80000000u);
}
__device__ __forceinline__ float deordf(unsigned u) {
    return __uint_as_float((u & 0x80000000u) ? (u ^ 0x80000000u) : ~u);
}
// bf16 round-to-nearest-even
__device__ __forceinline__ unsigned short bfr(float v) {
    unsigned u = __float_as_uint(v);
    u += 0x7FFFu + ((u >> 16) & 1u);
    return (unsigned short)(u >> 16);
}
__device__ __forceinline__ float ubf(unsigned short h) {
    return __uint_as_float(((unsigned)h) << 16);
}

// async global->LDS, 16B per lane; LDS dest is wave-uniform base (+lane*16 in HW)
#define GLD16(gp, lp) __builtin_amdgcn_global_load_lds(                         \
    (const __attribute__((address_space(1))) unsigned int*)(gp),                \
    (__attribute__((address_space(3))) unsigned int*)(lp), 16, 0, 0)

// 2 MFMAs + own nops + all 16 min3 folds in ONE asm unit (validated r11/r12).
#define TILE_STEP(ac, B0, B1, mA0, mB0, mA1, mB1)                          \
    asm("v_mfma_f32_32x32x16_bf16 v[32:47], %4, %5, 0\n\t"                 \
        "v_mfma_f32_32x32x16_bf16 v[48:63], %4, %6, 0\n\t"                 \
        "s_nop 7\n\t"                                                      \
        "s_nop 6\n\t"                                                      \
        "v_min3_f32 %0, %0, v32, v33\n\t"                                  \
        "v_min3_f32 %1, %1, v34, v35\n\t"                                  \
        "v_min3_f32 %0, %0, v36, v37\n\t"                                  \
        "v_min3_f32 %1, %1, v38, v39\n\t"                                  \
        "v_min3_f32 %0, %0, v40, v41\n\t"                                  \
        "v_min3_f32 %1, %1, v42, v43\n\t"                                  \
        "v_min3_f32 %0, %0, v44, v45\n\t"                                  \
        "v_min3_f32 %1, %1, v46, v47\n\t"                                  \
        "v_min3_f32 %2, %2, v48, v49\n\t"                                  \
        "v_min3_f32 %3, %3, v50, v51\n\t"                                  \
        "v_min3_f32 %2, %2, v52, v53\n\t"                                  \
        "v_min3_f32 %3, %3, v54, v55\n\t"                                  \
        "v_min3_f32 %2, %2, v56, v57\n\t"                                  \
        "v_min3_f32 %3, %3, v58, v59\n\t"                                  \
        "v_min3_f32 %2, %2, v60, v61\n\t"                                  \
        "v_min3_f32 %3, %3, v62, v63\n\t"                                  \
        : "+v"(mA0), "+v"(mB0), "+v"(mA1), "+v"(mB1)                       \
        : "v"(ac), "v"(B0), "v"(B1)                                        \
        : "v32","v33","v34","v35","v36","v37","v38","v39",                 \
          "v40","v41","v42","v43","v44","v45","v46","v47",                 \
          "v48","v49","v50","v51","v52","v53","v54","v55",                 \
          "v56","v57","v58","v59","v60","v61","v62","v63")

// K-slot assignment (11 of 16 used):
//  k:      0     1     2     3     4     5     6     7  |  8     9    10   11..15
//  A(ref): rhx   rlx   rhx   rhy   rly   rhy   rhz   rlz|  rhz   wh   wl   0
//  B(qry): -qhx  -qhx  -qlx  -qhy  -qhy  -qly  -qhz  -qhz| -qlz  1.0  1.0  0
// => D = 0.5|r|^2 - q.r  (C = literal 0 in the MFMA)
__global__ __launch_bounds__(256) void prep_kernel(const float* __restrict__ pred,
                                                   const float* __restrict__ target,
                                                   unsigned short* __restrict__ panel,
                                                   unsigned short* __restrict__ qpack,
                                                   float* __restrict__ wq,
                                                   unsigned* __restrict__ mins) {
    int t = blockIdx.x * 256 + threadIdx.x;      // 0..65535
    int cloud = t >> 15, r = t & 32767, b = r >> 14, i = r & 16383;
    const float* src = cloud ? target : pred;
    float x = src[(b * NPTS + i) * 3 + 0];
    float y = src[(b * NPTS + i) * 3 + 1];
    float zz = src[(b * NPTS + i) * 3 + 2];
    float w = 0.5f * (x * x + y * y + zz * zz);

    unsigned short hx = bfr(x),  lx = bfr(x - ubf(hx));
    unsigned short hy = bfr(y),  ly = bfr(y - ubf(hy));
    unsigned short hz = bfr(zz), lz = bfr(zz - ubf(hz));
    unsigned short hw = bfr(w),  lw = bfr(w - ubf(hw));

    const int slot = cloud * 2 + b;

    // A-panel: ref-major, 32B/ref, LDS-linear: ref i -> tile (i>>5), lane (i&31)
    unsigned short* pp = panel + ((size_t)slot << 18) + (size_t)(i >> 5) * 512 + (size_t)(i & 31) * 8;
    uint4 k0, k1;
    k0.x = hx | ((unsigned)lx << 16);
    k0.y = hx | ((unsigned)hy << 16);
    k0.z = ly | ((unsigned)hy << 16);
    k0.w = hz | ((unsigned)lz << 16);
    *(uint4*)pp = k0;
    k1.x = hz | ((unsigned)hw << 16);
    k1.y = lw;
    k1.z = 0; k1.w = 0;
    *(uint4*)(pp + 256) = k1;

    // B-pack: 32B/query, negated split (sign flip is exact)
    const unsigned short S = 0x8000u, ONE = 0x3F80u;
    unsigned short nhx = hx ^ S, nlx = lx ^ S, nhy = hy ^ S, nly = ly ^ S, nhz = hz ^ S, nlz = lz ^ S;
    unsigned short* qp = qpack + ((size_t)slot << 18) + (size_t)i * 16;
    uint4 qlo, qhi;
    qlo.x = nhx | ((unsigned)nhx << 16);
    qlo.y = nlx | ((unsigned)nhy << 16);
    qlo.z = nhy | ((unsigned)nly << 16);
    qlo.w = nhz | ((unsigned)nhz << 16);
    qhi.x = nlz | ((unsigned)ONE << 16);
    qhi.y = ONE;
    qhi.z = 0; qhi.w = 0;
    *(uint4*)qp = qlo;
    *(uint4*)(qp + 8) = qhi;

    wq[(slot << 14) | i] = w;
    mins[(slot << 14) | i] = 0xFFFFFFFFu;
}

// Persistent-style streaming: 512 blocks (2/CU), 8 chunks of 1024 refs each,
// double-buffered 64 KiB LDS, global_load_lds staging issued BEFORE compute.
__global__ __launch_bounds__(256) void nn_min_kernel(const unsigned short* __restrict__ panel,
                                                     const unsigned short* __restrict__ qpack,
                                                     unsigned* __restrict__ mins) {
    __shared__ __attribute__((aligned(16))) unsigned short lds_s[2 * 16384];  // 64 KiB

    const int z = blockIdx.z, b = z & 1, qc = z >> 1, rc = 1 - qc;
    const int tid = threadIdx.x, ln = tid & 63, wv = tid >> 6;

    const char* pblock = (const char*)(panel + (((size_t)(rc * 2 + b)) << 18)
                                       + (size_t)blockIdx.x * (RPB * 16));

    // ---- B fragments: 2 query-frags of 32 queries per wave ----
    const int qbase = blockIdx.y * QPB;
    const unsigned short* qb = qpack + (((size_t)(qc * 2 + b)) << 18);
    const int qcol = ln & 31, khalf = (ln >> 5) * 8;
    bf16x8 B0 = *(const bf16x8*)(qb + (size_t)(qbase + (wv * 2 + 0) * 32 + qcol) * 16 + khalf);
    bf16x8 B1 = *(const bf16x8*)(qb + (size_t)(qbase + (wv * 2 + 1) * 32 + qcol) * 16 + khalf);

    float mA0 = INFINITY, mB0 = INFINITY, mA1 = INFINITY, mB1 = INFINITY;

    // stage chunk c into LDS half h: 8 x 1KB wave-rounds; uniform LDS base per wave
#define STAGE(c, h) do {                                                        \
        const char* g_ = pblock + (size_t)(c) * 32768 + wv * 1024 + ln * 16;    \
        char* l_ = (char*)lds_s + (h) * 32768 + wv * 1024;                      \
        _Pragma("unroll")                                                       \
        for (int r_ = 0; r_ < 8; ++r_)                                          \
            GLD16(g_ + r_ * 4096, l_ + r_ * 4096);                              \
    } while (0)

#define COMPUTE(h) do {                                                         \
        const unsigned short* buf_ = lds_s + (h) * 16384;                       \
        bf16x8 a0 = *(const bf16x8*)&buf_[0 * 512 + ln * 8];                    \
        bf16x8 a1 = *(const bf16x8*)&buf_[1 * 512 + ln * 8];                    \
        _Pragma("unroll")                                                       \
        for (int t_ = 0; t_ < 32; t_ += 2) {                                    \
            bf16x8 n0 = a0, n1 = a1;                                            \
            if (t_ + 2 < 32) {                                                  \
                n0 = *(const bf16x8*)&buf_[(t_ + 2) * 512 + ln * 8];            \
                n1 = *(const bf16x8*)&buf_[(t_ + 3) * 512 + ln * 8];            \
            }                                                                   \
            TILE_STEP(a0, B0, B1, mA0, mB0, mA1, mB1);                          \
            TILE_STEP(a1, B0, B1, mA0, mB0, mA1, mB1);                          \
            a0 = n0; a1 = n1;                                                   \
        }                                                                       \
    } while (0)

    STAGE(0, 0);
    asm volatile("s_waitcnt vmcnt(0)" ::: "memory");
    __syncthreads();

    #pragma unroll
    for (int c = 0; c < NCH; ++c) {
        if (c + 1 < NCH) STAGE(c + 1, (c + 1) & 1);   // issue-early: hides under compute
        COMPUTE(c & 1);
        asm volatile("s_waitcnt vmcnt(0)" ::: "memory");
        __syncthreads();
    }
#undef STAGE
#undef COMPUTE

    unsigned* om = mins + ((size_t)z << 14) + qbase;
    atomicMin(&om[(wv * 2 + 0) * 32 + qcol], ordf(fminf(mA0, mB0)));
    atomicMin(&om[(wv * 2 + 1) * 32 + qcol], ordf(fminf(mA1, mB1)));
}

// d = sqrt(max(0, 2*(0.5|q|^2 + t_min)))
__global__ __launch_bounds__(256) void reduceA_kernel(const unsigned* __restrict__ mins,
                                                      const float* __restrict__ wq,
                                                      float* __restrict__ partials) {
    int base = blockIdx.x * 1024;
    float s = 0.f;
    #pragma unroll
    for (int k = 0; k < 4; ++k) {
        int t = base + k * 256 + threadIdx.x;
        float m = deordf(mins[t]);
        s += sqrtf(fmaxf(0.f, 2.f * (wq[t] + m)));
    }
    #pragma unroll
    for (int off = 32; off; off >>= 1) s += __shfl_down(s, off);
    __shared__ float wsum[4];
    int lane = threadIdx.x & 63, wv = threadIdx.x >> 6;
    if (lane == 0) wsum[wv] = s;
    __syncthreads();
    if (threadIdx.x == 0) partials[blockIdx.x] = wsum[0] + wsum[1] + wsum[2] + wsum[3];
}

__global__ void reduceB_kernel(const float* __restrict__ partials, float* __restrict__ out) {
    float s = partials[threadIdx.x];
    #pragma unroll
    for (int off = 32; off; off >>= 1) s += __shfl_down(s, off);
    if (threadIdx.x == 0) out[0] = s / (float)TOTQ;
}

extern "C" void kernel_launch(void* const* d_in, const int* in_sizes, int n_in,
                              void* d_out, int out_size, void* d_ws, size_t ws_size,
                              hipStream_t stream) {
    const float* pred   = (const float*)d_in[0];
    const float* target = (const float*)d_in[1];
    char* ws = (char*)d_ws;

    unsigned short* panel = (unsigned short*)ws;                              // 2 MiB
    unsigned short* qpack = (unsigned short*)(ws + (size_t)2 * 1024 * 1024);  // 2 MiB
    float*          wq    = (float*)(ws + (size_t)4 * 1024 * 1024);
    unsigned*       mins  = (unsigned*)(ws + (size_t)4 * 1024 * 1024 + 256 * 1024);
    float*       partials = (float*)(ws + (size_t)4 * 1024 * 1024 + 512 * 1024);
    float* out = (float*)d_out;

    prep_kernel<<<TOTMIN / 256, 256, 0, stream>>>(pred, target, panel, qpack, wq, mins);

    dim3 grid(NRC, NQC, 2 * NB);   // 2 x 64 x 4 = 512 blocks (2 per CU)
    nn_min_kernel<<<grid, 256, 0, stream>>>(panel, qpack, mins);

    reduceA_kernel<<<64, 256, 0, stream>>>(mins, wq, partials);
    reduceB_kernel<<<1, 64, 0, stream>>>(partials, out);
}

// Round 14
// 44.356 us; speedup vs baseline: 1.0176x; 1.0176x over previous
//
#include <hip/hip_runtime.h>
#include <math.h>

#define NPTS 16384
#define NB   2
#define RCH  1024               // refs per block (LDS tile), 32 KiB
#define NRC  (NPTS / RCH)       // 16
#define QPB  256                // queries per block: 4 waves * 2 frags * 32
#define NQC  (NPTS / QPB)       // 64
#define TOTQ (NB * NPTS)        // 32768
#define TOTMIN (2 * TOTQ)       // 65536

typedef short bf16x8 __attribute__((ext_vector_type(8)));

// monotone float <-> uint (t can be negative)
__device__ __forceinline__ unsigned ordf(float f) {
    unsigned b = __float_as_uint(f);
    return (b & 0x80000000u) ? ~b : (b | 0x80000000u);
}
__device__ __forceinline__ float deordf(unsigned u) {
    return __uint_as_float((u & 0x80000000u) ? (u ^ 0x80000000u) : ~u);
}
// bf16 round-to-nearest-even
__device__ __forceinline__ unsigned short bfr(float v) {
    unsigned u = __float_as_uint(v);
    u += 0x7FFFu + ((u >> 16) & 1u);
    return (unsigned short)(u >> 16);
}
__device__ __forceinline__ float ubf(unsigned short h) {
    return __uint_as_float(((unsigned)h) << 16);
}

// async global->LDS, 16B/lane; LDS dest wave-uniform base (+lane*16 in HW)
#define GLD16(gp, lp) __builtin_amdgcn_global_load_lds(                         \
    (const __attribute__((address_space(1))) unsigned int*)(gp),                \
    (__attribute__((address_space(3))) unsigned int*)(lp), 16, 0, 0)

// ---- hand-pipelined K-loop fragments (strings composed at preprocess time) ----
#define BUF0 "v[96:99]"
#define BUF1 "v[100:103]"
#define BUF2 "v[104:107]"
#define BUF3 "v[108:111]"
#define MF_A(AB) \
    "v_mfma_f32_32x32x16_bf16 v[32:47], " AB ", %[b0], 0\n\t" \
    "v_mfma_f32_32x32x16_bf16 v[48:63], " AB ", %[b1], 0\n\t"
#define MF_B(AB) \
    "v_mfma_f32_32x32x16_bf16 v[64:79], " AB ", %[b0], 0\n\t" \
    "v_mfma_f32_32x32x16_bf16 v[80:95], " AB ", %[b1], 0\n\t"
#define RD(AB, OFF) "ds_read_b128 " AB ", %[adr] offset:" OFF "\n\t"
#define W2 "s_waitcnt lgkmcnt(2)\n\t"
#define NOP7 "s_nop 7\n\t"
#define FOLD_A \
    "v_min3_f32 %[mA0], %[mA0], v32, v33\n\t" \
    "v_min3_f32 %[mB0], %[mB0], v34, v35\n\t" \
    "v_min3_f32 %[mA1], %[mA1], v48, v49\n\t" \
    "v_min3_f32 %[mB1], %[mB1], v50, v51\n\t" \
    "v_min3_f32 %[mA0], %[mA0], v36, v37\n\t" \
    "v_min3_f32 %[mB0], %[mB0], v38, v39\n\t" \
    "v_min3_f32 %[mA1], %[mA1], v52, v53\n\t" \
    "v_min3_f32 %[mB1], %[mB1], v54, v55\n\t" \
    "v_min3_f32 %[mA0], %[mA0], v40, v41\n\t" \
    "v_min3_f32 %[mB0], %[mB0], v42, v43\n\t" \
    "v_min3_f32 %[mA1], %[mA1], v56, v57\n\t" \
    "v_min3_f32 %[mB1], %[mB1], v58, v59\n\t" \
    "v_min3_f32 %[mA0], %[mA0], v44, v45\n\t" \
    "v_min3_f32 %[mB0], %[mB0], v46, v47\n\t" \
    "v_min3_f32 %[mA1], %[mA1], v60, v61\n\t" \
    "v_min3_f32 %[mB1], %[mB1], v62, v63\n\t"
#define FOLD_B \
    "v_min3_f32 %[mA0], %[mA0], v64, v65\n\t" \
    "v_min3_f32 %[mB0], %[mB0], v66, v67\n\t" \
    "v_min3_f32 %[mA1], %[mA1], v80, v81\n\t" \
    "v_min3_f32 %[mB1], %[mB1], v82, v83\n\t" \
    "v_min3_f32 %[mA0], %[mA0], v68, v69\n\t" \
    "v_min3_f32 %[mB0], %[mB0], v70, v71\n\t" \
    "v_min3_f32 %[mA1], %[mA1], v84, v85\n\t" \
    "v_min3_f32 %[mB1], %[mB1], v86, v87\n\t" \
    "v_min3_f32 %[mA0], %[mA0], v72, v73\n\t" \
    "v_min3_f32 %[mB0], %[mB0], v74, v75\n\t" \
    "v_min3_f32 %[mA1], %[mA1], v88, v89\n\t" \
    "v_min3_f32 %[mB1], %[mB1], v90, v91\n\t" \
    "v_min3_f32 %[mA0], %[mA0], v76, v77\n\t" \
    "v_min3_f32 %[mB0], %[mB0], v78, v79\n\t" \
    "v_min3_f32 %[mA1], %[mA1], v92, v93\n\t" \
    "v_min3_f32 %[mB1], %[mB1], v94, v95\n\t"
// steady-state group of 4 tiles (t = 4k..4k+3, k>=1): issue bank X, fold bank Y
#define G4(Oa, Ob, Oc, Od) \
    W2 MF_A(BUF0) RD(BUF3, Oa) NOP7 FOLD_B \
    W2 MF_B(BUF1) RD(BUF0, Ob) NOP7 FOLD_A \
    W2 MF_A(BUF2) RD(BUF1, Oc) NOP7 FOLD_B \
    W2 MF_B(BUF3) RD(BUF2, Od) NOP7 FOLD_A

// K-slot assignment (11 of 16 used):
//  k:      0     1     2     3     4     5     6     7  |  8     9    10   11..15
//  A(ref): rhx   rlx   rhx   rhy   rly   rhy   rhz   rlz|  rhz   wh   wl   0
//  B(qry): -qhx  -qhx  -qlx  -qhy  -qhy  -qly  -qhz  -qhz| -qlz  1.0  1.0  0
// => D = 0.5|r|^2 - q.r  (C = literal 0 in the MFMA)
__global__ __launch_bounds__(256) void prep_kernel(const float* __restrict__ pred,
                                                   const float* __restrict__ target,
                                                   unsigned short* __restrict__ panel,
                                                   unsigned short* __restrict__ qpack,
                                                   float* __restrict__ wq,
                                                   unsigned* __restrict__ mins) {
    int t = blockIdx.x * 256 + threadIdx.x;      // 0..65535
    int cloud = t >> 15, r = t & 32767, b = r >> 14, i = r & 16383;
    const float* src = cloud ? target : pred;
    float x = src[(b * NPTS + i) * 3 + 0];
    float y = src[(b * NPTS + i) * 3 + 1];
    float zz = src[(b * NPTS + i) * 3 + 2];
    float w = 0.5f * (x * x + y * y + zz * zz);

    unsigned short hx = bfr(x),  lx = bfr(x - ubf(hx));
    unsigned short hy = bfr(y),  ly = bfr(y - ubf(hy));
    unsigned short hz = bfr(zz), lz = bfr(zz - ubf(hz));
    unsigned short hw = bfr(w),  lw = bfr(w - ubf(hw));

    const int slot = cloud * 2 + b;

    // A-panel: ref-major, 32B/ref, LDS-linear: ref i -> tile (i>>5), lane (i&31)
    unsigned short* pp = panel + ((size_t)slot << 18) + (size_t)(i >> 5) * 512 + (size_t)(i & 31) * 8;
    uint4 k0, k1;
    k0.x = hx | ((unsigned)lx << 16);
    k0.y = hx | ((unsigned)hy << 16);
    k0.z = ly | ((unsigned)hy << 16);
    k0.w = hz | ((unsigned)lz << 16);
    *(uint4*)pp = k0;
    k1.x = hz | ((unsigned)hw << 16);
    k1.y = lw;
    k1.z = 0; k1.w = 0;
    *(uint4*)(pp + 256) = k1;

    // B-pack: 32B/query, negated split (sign flip is exact)
    const unsigned short S = 0x8000u, ONE = 0x3F80u;
    unsigned short nhx = hx ^ S, nlx = lx ^ S, nhy = hy ^ S, nly = ly ^ S, nhz = hz ^ S, nlz = lz ^ S;
    unsigned short* qp = qpack + ((size_t)slot << 18) + (size_t)i * 16;
    uint4 qlo, qhi;
    qlo.x = nhx | ((unsigned)nhx << 16);
    qlo.y = nlx | ((unsigned)nhy << 16);
    qlo.z = nhy | ((unsigned)nly << 16);
    qlo.w = nhz | ((unsigned)nhz << 16);
    qhi.x = nlz | ((unsigned)ONE << 16);
    qhi.y = ONE;
    qhi.z = 0; qhi.w = 0;
    *(uint4*)qp = qlo;
    *(uint4*)(qp + 8) = qhi;

    wq[(slot << 14) | i] = w;
    mins[(slot << 14) | i] = 0xFFFFFFFFu;
}

__global__ __launch_bounds__(256) void nn_min_kernel(const unsigned short* __restrict__ panel,
                                                     const unsigned short* __restrict__ qpack,
                                                     unsigned* __restrict__ mins) {
    __shared__ __attribute__((aligned(16))) unsigned short lds_s[RCH * 16];  // 32 KiB

    const int z = blockIdx.z, b = z & 1, qc = z >> 1, rc = 1 - qc;
    const int tid = threadIdx.x, ln = tid & 63, wv = tid >> 6;

    // ---- stage ref panel chunk -> LDS via global_load_lds (zero VGPR cost) ----
    const char* pbase = (const char*)(panel + (((size_t)(rc * 2 + b)) << 18)
                                      + (size_t)blockIdx.x * (RCH * 16));
    const char* g_ = pbase + wv * 1024 + ln * 16;
    char* l_ = (char*)lds_s + wv * 1024;
    #pragma unroll
    for (int r_ = 0; r_ < 8; ++r_)
        GLD16(g_ + r_ * 4096, l_ + r_ * 4096);

    // ---- B fragments: 2 query-frags of 32 queries per wave ----
    const int qbase = blockIdx.y * QPB;
    const unsigned short* qb = qpack + (((size_t)(qc * 2 + b)) << 18);
    const int qcol = ln & 31, khalf = (ln >> 5) * 8;
    bf16x8 B0 = *(const bf16x8*)(qb + (size_t)(qbase + (wv * 2 + 0) * 32 + qcol) * 16 + khalf);
    bf16x8 B1 = *(const bf16x8*)(qb + (size_t)(qbase + (wv * 2 + 1) * 32 + qcol) * 16 + khalf);

    asm volatile("s_waitcnt vmcnt(0)" ::: "memory");
    __syncthreads();

    // per-lane LDS byte address of this lane's A-fragment slot in tile 0
    unsigned adr = (unsigned)(unsigned long)
        (__attribute__((address_space(3))) char*)((char*)lds_s + ln * 16);

    float mA0 = INFINITY, mB0 = INFINITY, mA1 = INFINITY, mB1 = INFINITY;

    // Whole 32-tile K-loop in one asm block: dual D-banks (A=v[32:63], B=v[64:95])
    // alternate per tile; fold of tile t runs in step t+1 while the other bank's
    // MFMAs are in flight. 4 A-buffers v[96:111], 3-deep ds_read prefetch,
    // counted lgkmcnt (never drained mid-loop).
    asm volatile(
        RD(BUF0, "0") RD(BUF1, "1024") RD(BUF2, "2048")
        W2 MF_A(BUF0) RD(BUF3, "3072")                       // t0 (no fold)
        W2 MF_B(BUF1) RD(BUF0, "4096")  NOP7 FOLD_A          // t1
        W2 MF_A(BUF2) RD(BUF1, "5120")  NOP7 FOLD_B          // t2
        W2 MF_B(BUF3) RD(BUF2, "6144")  NOP7 FOLD_A          // t3
        G4("7168",  "8192",  "9216",  "10240")               // t4-7
        G4("11264", "12288", "13312", "14336")               // t8-11
        G4("15360", "16384", "17408", "18432")               // t12-15
        G4("19456", "20480", "21504", "22528")               // t16-19
        G4("23552", "24576", "25600", "26624")               // t20-23
        G4("27648", "28672", "29696", "30720")               // t24-27
        W2 MF_A(BUF0) RD(BUF3, "31744") NOP7 FOLD_B          // t28
        W2 MF_B(BUF1)                   NOP7 FOLD_A          // t29
        "s_waitcnt lgkmcnt(1)\n\t"
        MF_A(BUF2)                      NOP7 FOLD_B          // t30
        "s_waitcnt lgkmcnt(0)\n\t"
        MF_B(BUF3)                      NOP7 FOLD_A          // t31
        NOP7 NOP7 FOLD_B                                     // drain tile31
        : [mA0] "+v"(mA0), [mB0] "+v"(mB0), [mA1] "+v"(mA1), [mB1] "+v"(mB1)
        : [adr] "v"(adr), [b0] "v"(B0), [b1] "v"(B1)
        : "memory",
          "v32","v33","v34","v35","v36","v37","v38","v39",
          "v40","v41","v42","v43","v44","v45","v46","v47",
          "v48","v49","v50","v51","v52","v53","v54","v55",
          "v56","v57","v58","v59","v60","v61","v62","v63",
          "v64","v65","v66","v67","v68","v69","v70","v71",
          "v72","v73","v74","v75","v76","v77","v78","v79",
          "v80","v81","v82","v83","v84","v85","v86","v87",
          "v88","v89","v90","v91","v92","v93","v94","v95",
          "v96","v97","v98","v99","v100","v101","v102","v103",
          "v104","v105","v106","v107","v108","v109","v110","v111");

    unsigned* om = mins + ((size_t)z << 14) + qbase;
    atomicMin(&om[(wv * 2 + 0) * 32 + qcol], ordf(fminf(mA0, mB0)));
    atomicMin(&om[(wv * 2 + 1) * 32 + qcol], ordf(fminf(mA1, mB1)));
}

// d = sqrt(max(0, 2*(0.5|q|^2 + t_min)))
__global__ __launch_bounds__(256) void reduceA_kernel(const unsigned* __restrict__ mins,
                                                      const float* __restrict__ wq,
                                                      float* __restrict__ partials) {
    int base = blockIdx.x * 1024;
    float s = 0.f;
    #pragma unroll
    for (int k = 0; k < 4; ++k) {
        int t = base + k * 256 + threadIdx.x;
        float m = deordf(mins[t]);
        s += sqrtf(fmaxf(0.f, 2.f * (wq[t] + m)));
    }
    #pragma unroll
    for (int off = 32; off; off >>= 1) s += __shfl_down(s, off);
    __shared__ float wsum[4];
    int lane = threadIdx.x & 63, wv = threadIdx.x >> 6;
    if (lane == 0) wsum[wv] = s;
    __syncthreads();
    if (threadIdx.x == 0) partials[blockIdx.x] = wsum[0] + wsum[1] + wsum[2] + wsum[3];
}

__global__ void reduceB_kernel(const float* __restrict__ partials, float* __restrict__ out) {
    float s = partials[threadIdx.x];
    #pragma unroll
    for (int off = 32; off; off >>= 1) s += __shfl_down(s, off);
    if (threadIdx.x == 0) out[0] = s / (float)TOTQ;
}

extern "C" void kernel_launch(void* const* d_in, const int* in_sizes, int n_in,
                              void* d_out, int out_size, void* d_ws, size_t ws_size,
                              hipStream_t stream) {
    const float* pred   = (const float*)d_in[0];
    const float* target = (const float*)d_in[1];
    char* ws = (char*)d_ws;

    unsigned short* panel = (unsigned short*)ws;                              // 2 MiB
    unsigned short* qpack = (unsigned short*)(ws + (size_t)2 * 1024 * 1024);  // 2 MiB
    float*          wq    = (float*)(ws + (size_t)4 * 1024 * 1024);
    unsigned*       mins  = (unsigned*)(ws + (size_t)4 * 1024 * 1024 + 256 * 1024);
    float*       partials = (float*)(ws + (size_t)4 * 1024 * 1024 + 512 * 1024);
    float* out = (float*)d_out;

    prep_kernel<<<TOTMIN / 256, 256, 0, stream>>>(pred, target, panel, qpack, wq, mins);

    dim3 grid(NRC, NQC, 2 * NB);   // 16 x 64 x 4 = 4096 blocks
    nn_min_kernel<<<grid, 256, 0, stream>>>(panel, qpack, mins);

    reduceA_kernel<<<64, 256, 0, stream>>>(mins, wq, partials);
    reduceB_kernel<<<1, 64, 0, stream>>>(partials, out);
}